// Round 14
// baseline (143.669 us; speedup 1.0000x reference)
//
#include <hip/hip_runtime.h>
#include <math.h>

#define A_W 0.955f
#define B_W 1.3693f
#define INF_W 1e6f
#define HDIM 512
#define WDIM 512
#define NPIX (HDIM*WDIM)
#define NSAMP 16
#define NTOT_F 4194304.0f
#define TST 16      // strip height
#define NSTRIP 32   // strips per sample
#define STRIP_COST (16.0f * A_W)   // min cost to propagate a boundary through one strip

// ws layout (bytes):
//  [1024,3072):   int blkflags[512]  (per strip: bit0=has_fg, bit1=has_bg)
//  [4096,4100):   int counter        (last-block detection; zeroed by strip1a blk0)
//  [8192,20480):  float sacc[6][512]
//  [24576,28672): float mm1[2][512]  (min,max of Llast rows)
//  [28672,32768): float mm2[2][512]  (min,max of Llast2 rows)
//  [1MB,2MB):     float Llast[16][32][512]
//  [2MB,3MB):     float Llast2[16][32][512]
//  [3MB,19MB):    float dB[16][512][512]
#define OFF_CNT    4096
#define OFF_SACC   8192
#define OFF_MM1    24576
#define OFF_MM2    28672
#define OFF_LLAST  (1u<<20)
#define OFF_LLAST2 (2u<<20)
#define OFF_DB     (3u<<20)

// DPP move with INF fill (floats).
//   WAVE_SHR1 (0x138): lane i <- lane i-1 (== __shfl_up 1)
//   WAVE_SHL1 (0x130): lane i <- lane i+1 (== __shfl_down 1)
template<int CTRL, int RMASK>
__device__ __forceinline__ float dpp_mov_inf(float x) {
    return __int_as_float(__builtin_amdgcn_update_dpp(
        __float_as_int(INF_W), __float_as_int(x), CTRL, RMASK, 0xF, false));
}
template<int CTRL>
__device__ __forceinline__ int dpp_mov0_i(int x) {
    return __builtin_amdgcn_update_dpp(0, x, CTRL, 0xF, 0xF, true);
}

__device__ __forceinline__ float wave_prefix_min_incl(float t) {
    t = fminf(t, dpp_mov_inf<0x111,0xF>(t));
    t = fminf(t, dpp_mov_inf<0x112,0xF>(t));
    t = fminf(t, dpp_mov_inf<0x114,0xF>(t));
    t = fminf(t, dpp_mov_inf<0x118,0xF>(t));
    t = fminf(t, dpp_mov_inf<0x142,0xA>(t));
    t = fminf(t, dpp_mov_inf<0x143,0xC>(t));
    return t;
}

__device__ __forceinline__ void cummin_row(const float* jc, float* v) {
    float g[8];
#pragma unroll
    for (int i = 0; i < 8; ++i) g[i] = v[i] - jc[i];
    float c1[8];
    c1[0] = g[0];
#pragma unroll
    for (int i = 1; i < 8; ++i) c1[i] = fminf(g[i], g[i-1]);
    float c2[8];
    c2[0] = c1[0]; c2[1] = c1[1];
#pragma unroll
    for (int i = 2; i < 8; ++i) c2[i] = fminf(c1[i], c1[i-2]);
    float cj[8];
    cj[0] = c2[0]; cj[1] = c2[1]; cj[2] = c2[2]; cj[3] = c2[3];
#pragma unroll
    for (int i = 4; i < 8; ++i) cj[i] = fminf(c2[i], c2[i-4]);
    float t  = wave_prefix_min_incl(cj[7]);
    float ex = dpp_mov_inf<0x138,0xF>(t);
#pragma unroll
    for (int i = 0; i < 8; ++i) v[i] = jc[i] + fminf(cj[i], ex);
}

__device__ __forceinline__ void row_step(const float* jc, float* prev, const float* drow) {
    float lIn = dpp_mov_inf<0x138,0xF>(prev[7]);
    float rIn = dpp_mov_inf<0x130,0xF>(prev[0]);
    float m[8];
#pragma unroll
    for (int i = 0; i < 8; ++i) {
        float up = prev[i] + A_W;
        float ul = ((i == 0) ? lIn : prev[i-1]) + B_W;
        float ur = ((i == 7) ? rIn : prev[i+1]) + B_W;
        m[i] = fminf(fminf(drow[i], up), fminf(ul, ur));
    }
    cummin_row(jc, m);
#pragma unroll
    for (int i = 0; i < 8; ++i) prev[i] = m[i];
}

// 4 fused T3 steps (exact, INF outside grid).
__device__ __forceinline__ void t3x4(float* b) {
    float e[16];
#pragma unroll
    for (int k = 0; k < 4; ++k) e[k]    = dpp_mov_inf<0x138,0xF>(b[4+k]);
#pragma unroll
    for (int k = 0; k < 8; ++k) e[4+k]  = b[k];
#pragma unroll
    for (int k = 0; k < 4; ++k) e[12+k] = dpp_mov_inf<0x130,0xF>(b[k]);
    const float w0 = 4.f*A_W, w1 = 3.f*A_W + B_W, w2 = 2.f*A_W + 2.f*B_W;
    const float w3 = A_W + 3.f*B_W, w4 = 4.f*B_W;
#pragma unroll
    for (int i = 0; i < 8; ++i) {
        float m = e[i+4] + w0;
        m = fminf(m, fminf(e[i+3], e[i+5]) + w1);
        m = fminf(m, fminf(e[i+2], e[i+6]) + w2);
        m = fminf(m, fminf(e[i+1], e[i+7]) + w3);
        m = fminf(m, fminf(e[i+0], e[i+8]) + w4);
        b[i] = m;
    }
}

struct RowBits { int efg; int ebg; int rawbg; };

__device__ __forceinline__ RowBits make_rowbits(uint4 a, uint4 b) {
    int fg = ((a.x!=0u)?1:0) | ((a.y!=0u)?2:0) | ((a.z!=0u)?4:0) | ((a.w!=0u)?8:0)
           | ((b.x!=0u)?16:0) | ((b.y!=0u)?32:0) | ((b.z!=0u)?64:0) | ((b.w!=0u)?128:0);
    int bg = (~fg) & 0xFF;
    int lf = dpp_mov0_i<0x138>(fg), rf = dpp_mov0_i<0x130>(fg);
    int lb = dpp_mov0_i<0x138>(bg), rb = dpp_mov0_i<0x130>(bg);
    RowBits r;
    r.efg = (fg | (fg<<1) | (fg>>1) | ((lf>>7)&1) | ((rf&1)<<7)) & 0xFF;
    r.ebg = (bg | (bg<<1) | (bg>>1) | ((lb>>7)&1) | ((rb&1)<<7)) & 0xFF;
    r.rawbg = bg;
    return r;
}

__device__ __forceinline__ RowBits loadrow_bits(const int* tgb, int rr, int c0) {
    if (rr < 0 || rr >= HDIM) { RowBits z; z.efg = 0; z.ebg = 0; z.rawbg = 0; return z; }
    const uint4* p = (const uint4*)(tgb + (size_t)rr * WDIM + c0);
    return make_rowbits(p[0], p[1]);
}

// store min/max of an L row (prev[8] across wave) into mm arrays
__device__ __forceinline__ void store_minmax(const float* prev, float* __restrict__ mm,
                                             int idx, int lane) {
    float mn = prev[0], mx = prev[0];
#pragma unroll
    for (int i = 1; i < 8; ++i) { mn = fminf(mn, prev[i]); mx = fmaxf(mx, prev[i]); }
#pragma unroll
    for (int off = 32; off > 0; off >>= 1) {
        mn = fminf(mn, __shfl_xor(mn, off));
        mx = fmaxf(mx, __shfl_xor(mx, off));
    }
    if (lane == 0) { mm[idx] = mn; mm[512 + idx] = mx; }
}

// Inline exact boundary with dominance pruning (exact: ties kept via strict >).
__device__ __forceinline__ void inline_bounds(const float* __restrict__ Lb, int n,
                                              const float* jc, int c0, float* prev,
                                              const float* __restrict__ mm, int base,
                                              int lane) {
    float ub = mm[512 + base + (n - 1)];                 // maxL[n-1]
    int k = lane;
    bool cond = (k < n) && (mm[base + k] + STRIP_COST * (float)(n - 1 - k) <= ub);
    unsigned long long msk = __ballot((int)cond);
    int k0 = (msk != 0ull) ? (__ffsll((long long)msk) - 1) : (n - 1);

    float b[8];
    const float* Lr = Lb + (size_t)k0 * WDIM + c0;
    float4 l0 = *(const float4*)Lr;
    float4 l1 = *(const float4*)(Lr + 4);
    b[0]=l0.x; b[1]=l0.y; b[2]=l0.z; b[3]=l0.w;
    b[4]=l1.x; b[5]=l1.y; b[6]=l1.z; b[7]=l1.w;
    for (int sg = k0 + 1; sg < n; ++sg) {
        const float* Ls = Lb + (size_t)sg * WDIM + c0;
        float4 m0 = *(const float4*)Ls;
        float4 m1 = *(const float4*)(Ls + 4);
        t3x4(b); t3x4(b); t3x4(b); t3x4(b);      // T3^16 exact (TST==16)
        cummin_row(jc, b);
        b[0]=fminf(b[0],m0.x); b[1]=fminf(b[1],m0.y); b[2]=fminf(b[2],m0.z); b[3]=fminf(b[3],m0.w);
        b[4]=fminf(b[4],m1.x); b[5]=fminf(b[5],m1.y); b[6]=fminf(b[6],m1.z); b[7]=fminf(b[7],m1.w);
    }
#pragma unroll
    for (int i = 0; i < 8; ++i) prev[i] = b[i];
}

// K1: pass-1 local strip scan (always boundary seeds; INF incoming) -> Llast + mm1
//     + per-strip fg/bg flags. Block 0 zeroes the last-block counter.
__global__ __launch_bounds__(64) void strip1a_kernel(const int* __restrict__ tg,
                                                     float* __restrict__ Llast,
                                                     float* __restrict__ mm1,
                                                     int* __restrict__ blkflags,
                                                     int* __restrict__ counter) {
    const int s = blockIdx.x >> 5, sig = blockIdx.x & 31;
    const int lane = threadIdx.x;
    const int c0 = lane * 8;
    const int* tgb = tg + (size_t)s * NPIX;
    const int R0 = sig * TST;
    if (blockIdx.x == 0 && lane == 0) *counter = 0;
    float jc[8];
#pragma unroll
    for (int i = 0; i < 8; ++i) jc[i] = A_W * (float)(c0 + i);
    RowBits rA = loadrow_bits(tgb, R0 - 1, c0);
    RowBits rB = loadrow_bits(tgb, R0, c0);
    float prev[8];
#pragma unroll
    for (int i = 0; i < 8; ++i) prev[i] = INF_W;
    int fgor = 0, bgor = 0;
#pragma unroll 4
    for (int t = 0; t < TST; ++t) {
        RowBits rC = loadrow_bits(tgb, R0 + t + 1, c0);
        fgor |= (~rB.rawbg) & 0xFF;
        bgor |= rB.rawbg;
        int smask = (rA.efg | rB.efg | rC.efg) & (rA.ebg | rB.ebg | rC.ebg);
        float dr[8];
#pragma unroll
        for (int i = 0; i < 8; ++i) dr[i] = ((smask >> i) & 1) ? 0.f : INF_W;
        row_step(jc, prev, dr);
        rA = rB; rB = rC;
    }
    float* Lr = Llast + ((size_t)s * NSTRIP + sig) * WDIM + c0;
    *(float4*)Lr       = make_float4(prev[0], prev[1], prev[2], prev[3]);
    *(float4*)(Lr + 4) = make_float4(prev[4], prev[5], prev[6], prev[7]);
    store_minmax(prev, mm1, s * NSTRIP + sig, lane);
    int wf = __any(fgor != 0) ? 1 : 0;
    int wb = __any(bgor != 0) ? 2 : 0;
    if (lane == 0) blkflags[blockIdx.x] = wf | wb;
}

// K2: pruned bounds1 + exact pass-1 rows -> dB (+LDS) + flipped local scan -> Llast2 + mm2.
__global__ __launch_bounds__(64) void strip3ab_kernel(const int* __restrict__ tg,
                                                      const float* __restrict__ Llast,
                                                      const float* __restrict__ mm1,
                                                      float* __restrict__ dB,
                                                      float* __restrict__ Llast2,
                                                      float* __restrict__ mm2) {
    const int s = blockIdx.x >> 5, sig = blockIdx.x & 31;
    const int lane = threadIdx.x;
    const int c0 = lane * 8;
    const int* tgb = tg + (size_t)s * NPIX;
    const int R0 = sig * TST;
    float jc[8];
#pragma unroll
    for (int i = 0; i < 8; ++i) jc[i] = A_W * (float)(c0 + i);

    __shared__ float lds[TST][WDIM];   // 32 KB; single-wave block

    float prev[8];
    if (sig == 0) {
#pragma unroll
        for (int i = 0; i < 8; ++i) prev[i] = INF_W;
    } else {
        inline_bounds(Llast + (size_t)s * NSTRIP * WDIM, sig, jc, c0, prev,
                      mm1, s * NSTRIP, lane);
    }

    RowBits rA = loadrow_bits(tgb, R0 - 1, c0);
    RowBits rB = loadrow_bits(tgb, R0, c0);
    float* dst = dB + (size_t)s * NPIX + (size_t)R0 * WDIM;
#pragma unroll 2
    for (int t = 0; t < TST; ++t) {
        RowBits rC = loadrow_bits(tgb, R0 + t + 1, c0);
        int smask = (rA.efg | rB.efg | rC.efg) & (rA.ebg | rB.ebg | rC.ebg);
        float dr[8];
#pragma unroll
        for (int i = 0; i < 8; ++i) dr[i] = ((smask >> i) & 1) ? 0.f : INF_W;
        row_step(jc, prev, dr);
        float* p = dst + (size_t)t * WDIM + c0;
        *(float4*)p       = make_float4(prev[0], prev[1], prev[2], prev[3]);
        *(float4*)(p + 4) = make_float4(prev[4], prev[5], prev[6], prev[7]);
        *(float4*)&lds[t][c0]     = make_float4(prev[0], prev[1], prev[2], prev[3]);
        *(float4*)&lds[t][c0 + 4] = make_float4(prev[4], prev[5], prev[6], prev[7]);
        rA = rB; rB = rC;
    }
    __syncthreads();
    // flipped (pass-2) local scan over this strip, INF incoming
#pragma unroll
    for (int i = 0; i < 8; ++i) prev[i] = INF_W;
#pragma unroll 2
    for (int t2 = 0; t2 < TST; ++t2) {
        float4 a = *(const float4*)&lds[TST - 1 - t2][504 - c0];
        float4 q = *(const float4*)&lds[TST - 1 - t2][508 - c0];
        float dr[8];
        dr[7]=a.x; dr[6]=a.y; dr[5]=a.z; dr[4]=a.w;
        dr[3]=q.x; dr[2]=q.y; dr[1]=q.z; dr[0]=q.w;
        row_step(jc, prev, dr);
    }
    const int sig2 = 31 - sig;
    float* Lr = Llast2 + ((size_t)s * NSTRIP + sig2) * WDIM + c0;
    *(float4*)Lr       = make_float4(prev[0], prev[1], prev[2], prev[3]);
    *(float4*)(Lr + 4) = make_float4(prev[4], prev[5], prev[6], prev[7]);
    store_minmax(prev, mm2, s * NSTRIP + sig2, lane);
}

// K3: pruned bounds2 + pass-2 exact rows + fused loss -> sacc; LAST block runs final.
__global__ __launch_bounds__(64) void strip3bloss_kernel(const float* __restrict__ dB,
                                                         const float* __restrict__ Llast2,
                                                         const float* __restrict__ mm2,
                                                         const float* __restrict__ pred,
                                                         const int* __restrict__ tg,
                                                         float* __restrict__ sacc,
                                                         const int* __restrict__ blkflags,
                                                         int* __restrict__ counter,
                                                         const float* __restrict__ lv,
                                                         float* __restrict__ out) {
    const int s = blockIdx.x >> 5, sig2 = blockIdx.x & 31;
    const int lane = threadIdx.x;
    const int c0 = lane * 8;
    const size_t sb = (size_t)s * NPIX;
    float jc[8];
#pragma unroll
    for (int i = 0; i < 8; ++i) jc[i] = A_W * (float)(c0 + i);

    float prev[8];
    if (sig2 == 0) {
#pragma unroll
        for (int i = 0; i < 8; ++i) prev[i] = INF_W;
    } else {
        inline_bounds(Llast2 + (size_t)s * NSTRIP * WDIM, sig2, jc, c0, prev,
                      mm2, s * NSTRIP, lane);
    }

    float mx = 0.f, facc = 0.f, s1 = 0.f, s2 = 0.f, iacc = 0.f, pacc = 0.f;
#pragma unroll 2
    for (int t = 0; t < TST; ++t) {
        int pr = HDIM - 1 - (sig2 * TST + t);
        const size_t rbase = sb + (size_t)pr * WDIM + (WDIM - 8 - c0);
        float4 a = *(const float4*)(dB + rbase);
        float4 b = *(const float4*)(dB + rbase + 4);
        float dr[8];
        dr[7]=a.x; dr[6]=a.y; dr[5]=a.z; dr[4]=a.w;
        dr[3]=b.x; dr[2]=b.y; dr[1]=b.z; dr[0]=b.w;
        float4 xa = *(const float4*)(pred + rbase);
        float4 xb = *(const float4*)(pred + rbase + 4);
        float px[8];
        px[7]=xa.x; px[6]=xa.y; px[5]=xa.z; px[4]=xa.w;
        px[3]=xb.x; px[2]=xb.y; px[1]=xb.z; px[0]=xb.w;
        int4 ta = *(const int4*)(tg + rbase);
        int4 tb = *(const int4*)(tg + rbase + 4);
        int ti[8];
        ti[7]=ta.x; ti[6]=ta.y; ti[5]=ta.z; ti[4]=ta.w;
        ti[3]=tb.x; ti[2]=tb.y; ti[1]=tb.z; ti[0]=tb.w;
        row_step(jc, prev, dr);
#pragma unroll
        for (int i = 0; i < 8; ++i) {
            float x = px[i];
            float dd = prev[i];
            float e = __expf(-fabsf(x));
            float inv = 1.f / (1.f + e);
            float pr_ = (x >= 0.f) ? inv : (1.f - inv);   // sigmoid(x)
            float L = __logf(1.f + e);                    // softplus(-|x|)
            bool t1 = ti[i] != 0;
            float fo = t1 ? 0.25f * (1.f - pr_) * (1.f - pr_) * (fmaxf(-x, 0.f) + L)
                          : 0.75f * pr_ * pr_ * (fmaxf(x, 0.f) + L);
            facc += fo;
            float base = t1 ? (1.f - pr_) : pr_;
            s1 += base;
            s2 += base * dd;
            float tf = t1 ? 1.f : 0.f;
            iacc += tf * pr_;
            pacc += pr_ + tf;
            mx = fmaxf(mx, dd);
        }
    }
#pragma unroll
    for (int off = 32; off > 0; off >>= 1) {
        facc += __shfl_xor(facc, off);
        s1   += __shfl_xor(s1, off);
        s2   += __shfl_xor(s2, off);
        iacc += __shfl_xor(iacc, off);
        pacc += __shfl_xor(pacc, off);
        mx    = fmaxf(mx, __shfl_xor(mx, off));
    }
    if (lane == 0) {
        const int idx = s * NSTRIP + sig2;
        sacc[0 * 512 + idx] = s1;
        sacc[1 * 512 + idx] = s2;
        sacc[2 * 512 + idx] = iacc;
        sacc[3 * 512 + idx] = pacc;
        sacc[4 * 512 + idx] = mx;
        sacc[5 * 512 + idx] = facc;
    }
    // ---- last-block final reduction ----
    __threadfence();                       // release our sacc stores
    int old = 0;
    if (lane == 0) old = atomicAdd(counter, 1);
    old = __shfl(old, 0);
    if (old == NSAMP * NSTRIP - 1) {
        __threadfence();                   // acquire all blocks' sacc stores
        const int j = lane & 31;
        float fsum = 0.f, bsum = 0.f, dsum = 0.f, isum = 0.f;
        for (int k = 0; k < 8; ++k) {
            int ss = 2 * k + (lane >> 5);
            int idx = ss * NSTRIP + j;
            float t1 = sacc[0 * 512 + idx];
            float t2 = sacc[1 * 512 + idx];
            float ia = sacc[2 * 512 + idx];
            float pa = sacc[3 * 512 + idx];
            float mxs = sacc[4 * 512 + idx];
            float fa = sacc[5 * 512 + idx];
            int   vv = blkflags[ss * 32 + j];
#pragma unroll
            for (int off = 16; off > 0; off >>= 1) {
                t1 += __shfl_xor(t1, off);
                t2 += __shfl_xor(t2, off);
                ia += __shfl_xor(ia, off);
                pa += __shfl_xor(pa, off);
                fa += __shfl_xor(fa, off);
                mxs = fmaxf(mxs, __shfl_xor(mxs, off));
                vv |= __shfl_xor(vv, off);
            }
            bool hasb = (vv & 3) == 3;     // boundary nonempty
            if (j == 0) {
                fsum += fa;
                // hasb: dist = d/mx (mx>0). !hasb: dist ≡ 1 (both all-fg and all-bg) -> S1.
                float distsum = hasb ? ((mxs > 0.f) ? t2 / fmaxf(mxs, 1e-12f) : 0.f) : t1;
                bsum += t1 + distsum;
                dsum += (2.f * ia + 1e-6f) / (pa + 1e-6f);
                isum += (ia + 1e-6f) / (pa - ia + 1e-6f);
            }
        }
        fsum += __shfl_xor(fsum, 32);
        bsum += __shfl_xor(bsum, 32);
        dsum += __shfl_xor(dsum, 32);
        isum += __shfl_xor(isum, 32);
        if (lane == 0) {
            float focal = fsum / NTOT_F;
            float bnd   = bsum / NTOT_F;
            float dice = 1.f - dsum / 16.f;
            float iou  = 1.f - isum / 16.f;
            float l0 = lv[0], l1 = lv[1], l2 = lv[2], l3 = lv[3];
            float total = expf(-l0) * focal + l0 + expf(-l1) * dice + l1
                        + expf(-l2) * bnd  + l2 + expf(-l3) * iou  + l3;
            out[0] = total; out[1] = focal; out[2] = dice; out[3] = bnd; out[4] = iou;
        }
    }
}

extern "C" void kernel_launch(void* const* d_in, const int* in_sizes, int n_in,
                              void* d_out, int out_size, void* d_ws, size_t ws_size,
                              hipStream_t stream) {
    const float* pred = (const float*)d_in[0];
    const int*   tg   = (const int*)d_in[1];
    const float* lv   = (const float*)d_in[2];
    float* out = (float*)d_out;
    char* ws = (char*)d_ws;
    int*   blkflags = (int*)(ws + 1024);
    int*   counter  = (int*)(ws + OFF_CNT);
    float* sacc     = (float*)(ws + OFF_SACC);
    float* mm1      = (float*)(ws + OFF_MM1);
    float* mm2      = (float*)(ws + OFF_MM2);
    float* Llast    = (float*)(ws + OFF_LLAST);
    float* Llast2   = (float*)(ws + OFF_LLAST2);
    float* dB       = (float*)(ws + OFF_DB);

    strip1a_kernel<<<NSAMP * NSTRIP, 64, 0, stream>>>(tg, Llast, mm1, blkflags, counter);
    strip3ab_kernel<<<NSAMP * NSTRIP, 64, 0, stream>>>(tg, Llast, mm1, dB, Llast2, mm2);
    strip3bloss_kernel<<<NSAMP * NSTRIP, 64, 0, stream>>>(dB, Llast2, mm2, pred, tg, sacc,
                                                          blkflags, counter, lv, out);
}

// Round 15
// 117.442 us; speedup vs baseline: 1.2233x; 1.2233x over previous
//
#include <hip/hip_runtime.h>
#include <math.h>

#define A_W 0.955f
#define B_W 1.3693f
#define INF_W 1e6f
#define HDIM 512
#define WDIM 512
#define NPIX (HDIM*WDIM)
#define NSAMP 16
#define NTOT_F 4194304.0f
#define TST 8       // strip height (was 16; halves serial chain, doubles occupancy)
#define NSTRIP 64   // strips per sample
#define NBLK (NSAMP*NSTRIP)        // 1024
#define STRIP_COST (8.0f * A_W)    // min cost to propagate a boundary through one strip

// ws layout (bytes):
//  [1024,5120):    int blkflags[1024]  (per strip: bit0=has_fg, bit1=has_bg)
//  [8192,32768):   float sacc[6][1024]
//  [32768,40960):  float mm1[2][1024]  (min,max of Llast rows)
//  [40960,49152):  float mm2[2][1024]  (min,max of Llast2 rows)
//  [1MB,3MB):      float Llast[16][64][512]
//  [3MB,5MB):      float Llast2[16][64][512]
//  [5MB,21MB):     float dB[16][512][512]
#define OFF_SACC   8192
#define OFF_MM1    32768
#define OFF_MM2    40960
#define OFF_LLAST  (1u<<20)
#define OFF_LLAST2 (3u<<20)
#define OFF_DB     (5u<<20)

// DPP move with INF fill (floats).
//   WAVE_SHR1 (0x138): lane i <- lane i-1 (== __shfl_up 1)
//   WAVE_SHL1 (0x130): lane i <- lane i+1 (== __shfl_down 1)
template<int CTRL, int RMASK>
__device__ __forceinline__ float dpp_mov_inf(float x) {
    return __int_as_float(__builtin_amdgcn_update_dpp(
        __float_as_int(INF_W), __float_as_int(x), CTRL, RMASK, 0xF, false));
}
template<int CTRL>
__device__ __forceinline__ int dpp_mov0_i(int x) {
    return __builtin_amdgcn_update_dpp(0, x, CTRL, 0xF, 0xF, true);
}

__device__ __forceinline__ float wave_prefix_min_incl(float t) {
    t = fminf(t, dpp_mov_inf<0x111,0xF>(t));
    t = fminf(t, dpp_mov_inf<0x112,0xF>(t));
    t = fminf(t, dpp_mov_inf<0x114,0xF>(t));
    t = fminf(t, dpp_mov_inf<0x118,0xF>(t));
    t = fminf(t, dpp_mov_inf<0x142,0xA>(t));
    t = fminf(t, dpp_mov_inf<0x143,0xC>(t));
    return t;
}

__device__ __forceinline__ void cummin_row(const float* jc, float* v) {
    float g[8];
#pragma unroll
    for (int i = 0; i < 8; ++i) g[i] = v[i] - jc[i];
    float c1[8];
    c1[0] = g[0];
#pragma unroll
    for (int i = 1; i < 8; ++i) c1[i] = fminf(g[i], g[i-1]);
    float c2[8];
    c2[0] = c1[0]; c2[1] = c1[1];
#pragma unroll
    for (int i = 2; i < 8; ++i) c2[i] = fminf(c1[i], c1[i-2]);
    float cj[8];
    cj[0] = c2[0]; cj[1] = c2[1]; cj[2] = c2[2]; cj[3] = c2[3];
#pragma unroll
    for (int i = 4; i < 8; ++i) cj[i] = fminf(c2[i], c2[i-4]);
    float t  = wave_prefix_min_incl(cj[7]);
    float ex = dpp_mov_inf<0x138,0xF>(t);
#pragma unroll
    for (int i = 0; i < 8; ++i) v[i] = jc[i] + fminf(cj[i], ex);
}

__device__ __forceinline__ void row_step(const float* jc, float* prev, const float* drow) {
    float lIn = dpp_mov_inf<0x138,0xF>(prev[7]);
    float rIn = dpp_mov_inf<0x130,0xF>(prev[0]);
    float m[8];
#pragma unroll
    for (int i = 0; i < 8; ++i) {
        float up = prev[i] + A_W;
        float ul = ((i == 0) ? lIn : prev[i-1]) + B_W;
        float ur = ((i == 7) ? rIn : prev[i+1]) + B_W;
        m[i] = fminf(fminf(drow[i], up), fminf(ul, ur));
    }
    cummin_row(jc, m);
#pragma unroll
    for (int i = 0; i < 8; ++i) prev[i] = m[i];
}

// 4 fused T3 steps (exact, INF outside grid).
__device__ __forceinline__ void t3x4(float* b) {
    float e[16];
#pragma unroll
    for (int k = 0; k < 4; ++k) e[k]    = dpp_mov_inf<0x138,0xF>(b[4+k]);
#pragma unroll
    for (int k = 0; k < 8; ++k) e[4+k]  = b[k];
#pragma unroll
    for (int k = 0; k < 4; ++k) e[12+k] = dpp_mov_inf<0x130,0xF>(b[k]);
    const float w0 = 4.f*A_W, w1 = 3.f*A_W + B_W, w2 = 2.f*A_W + 2.f*B_W;
    const float w3 = A_W + 3.f*B_W, w4 = 4.f*B_W;
#pragma unroll
    for (int i = 0; i < 8; ++i) {
        float m = e[i+4] + w0;
        m = fminf(m, fminf(e[i+3], e[i+5]) + w1);
        m = fminf(m, fminf(e[i+2], e[i+6]) + w2);
        m = fminf(m, fminf(e[i+1], e[i+7]) + w3);
        m = fminf(m, fminf(e[i+0], e[i+8]) + w4);
        b[i] = m;
    }
}

struct RowBits { int efg; int ebg; int rawbg; };

__device__ __forceinline__ RowBits make_rowbits(uint4 a, uint4 b) {
    int fg = ((a.x!=0u)?1:0) | ((a.y!=0u)?2:0) | ((a.z!=0u)?4:0) | ((a.w!=0u)?8:0)
           | ((b.x!=0u)?16:0) | ((b.y!=0u)?32:0) | ((b.z!=0u)?64:0) | ((b.w!=0u)?128:0);
    int bg = (~fg) & 0xFF;
    int lf = dpp_mov0_i<0x138>(fg), rf = dpp_mov0_i<0x130>(fg);
    int lb = dpp_mov0_i<0x138>(bg), rb = dpp_mov0_i<0x130>(bg);
    RowBits r;
    r.efg = (fg | (fg<<1) | (fg>>1) | ((lf>>7)&1) | ((rf&1)<<7)) & 0xFF;
    r.ebg = (bg | (bg<<1) | (bg>>1) | ((lb>>7)&1) | ((rb&1)<<7)) & 0xFF;
    r.rawbg = bg;
    return r;
}

__device__ __forceinline__ RowBits loadrow_bits(const int* tgb, int rr, int c0) {
    if (rr < 0 || rr >= HDIM) { RowBits z; z.efg = 0; z.ebg = 0; z.rawbg = 0; return z; }
    const uint4* p = (const uint4*)(tgb + (size_t)rr * WDIM + c0);
    return make_rowbits(p[0], p[1]);
}

// store min/max of an L row (prev[8] across wave) into mm arrays
__device__ __forceinline__ void store_minmax(const float* prev, float* __restrict__ mm,
                                             int idx, int lane) {
    float mn = prev[0], mx = prev[0];
#pragma unroll
    for (int i = 1; i < 8; ++i) { mn = fminf(mn, prev[i]); mx = fmaxf(mx, prev[i]); }
#pragma unroll
    for (int off = 32; off > 0; off >>= 1) {
        mn = fminf(mn, __shfl_xor(mn, off));
        mx = fmaxf(mx, __shfl_xor(mx, off));
    }
    if (lane == 0) { mm[idx] = mn; mm[NBLK + idx] = mx; }
}

// Inline exact boundary with dominance pruning (exact: ties kept via strict >).
// Strip k skippable when minL[k] + STRIP_COST*(n-1-k) > maxL[n-1]
// (each row of propagation adds >= A; b*[j] <= L[n-1][j] <= maxL[n-1]).
__device__ __forceinline__ void inline_bounds(const float* __restrict__ Lb, int n,
                                              const float* jc, int c0, float* prev,
                                              const float* __restrict__ mm, int base,
                                              int lane) {
    float ub = mm[NBLK + base + (n - 1)];                // maxL[n-1]
    int k = lane;
    bool cond = (k < n) && (mm[base + k] + STRIP_COST * (float)(n - 1 - k) <= ub);
    unsigned long long msk = __ballot((int)cond);
    int k0 = (msk != 0ull) ? (__ffsll((long long)msk) - 1) : (n - 1);

    float b[8];
    const float* Lr = Lb + (size_t)k0 * WDIM + c0;
    float4 l0 = *(const float4*)Lr;
    float4 l1 = *(const float4*)(Lr + 4);
    b[0]=l0.x; b[1]=l0.y; b[2]=l0.z; b[3]=l0.w;
    b[4]=l1.x; b[5]=l1.y; b[6]=l1.z; b[7]=l1.w;
    for (int sg = k0 + 1; sg < n; ++sg) {
        const float* Ls = Lb + (size_t)sg * WDIM + c0;
        float4 m0 = *(const float4*)Ls;
        float4 m1 = *(const float4*)(Ls + 4);
        t3x4(b); t3x4(b);                        // T3^8 exact (TST==8)
        cummin_row(jc, b);
        b[0]=fminf(b[0],m0.x); b[1]=fminf(b[1],m0.y); b[2]=fminf(b[2],m0.z); b[3]=fminf(b[3],m0.w);
        b[4]=fminf(b[4],m1.x); b[5]=fminf(b[5],m1.y); b[6]=fminf(b[6],m1.z); b[7]=fminf(b[7],m1.w);
    }
#pragma unroll
    for (int i = 0; i < 8; ++i) prev[i] = b[i];
}

// K1: pass-1 local strip scan (boundary seeds; INF incoming) -> Llast + mm1 + flags.
__global__ __launch_bounds__(64) void strip1a_kernel(const int* __restrict__ tg,
                                                     float* __restrict__ Llast,
                                                     float* __restrict__ mm1,
                                                     int* __restrict__ blkflags) {
    const int s = blockIdx.x >> 6, sig = blockIdx.x & 63;
    const int lane = threadIdx.x;
    const int c0 = lane * 8;
    const int* tgb = tg + (size_t)s * NPIX;
    const int R0 = sig * TST;
    float jc[8];
#pragma unroll
    for (int i = 0; i < 8; ++i) jc[i] = A_W * (float)(c0 + i);
    RowBits rA = loadrow_bits(tgb, R0 - 1, c0);
    RowBits rB = loadrow_bits(tgb, R0, c0);
    float prev[8];
#pragma unroll
    for (int i = 0; i < 8; ++i) prev[i] = INF_W;
    int fgor = 0, bgor = 0;
#pragma unroll 4
    for (int t = 0; t < TST; ++t) {
        RowBits rC = loadrow_bits(tgb, R0 + t + 1, c0);
        fgor |= (~rB.rawbg) & 0xFF;
        bgor |= rB.rawbg;
        int smask = (rA.efg | rB.efg | rC.efg) & (rA.ebg | rB.ebg | rC.ebg);
        float dr[8];
#pragma unroll
        for (int i = 0; i < 8; ++i) dr[i] = ((smask >> i) & 1) ? 0.f : INF_W;
        row_step(jc, prev, dr);
        rA = rB; rB = rC;
    }
    float* Lr = Llast + ((size_t)s * NSTRIP + sig) * WDIM + c0;
    *(float4*)Lr       = make_float4(prev[0], prev[1], prev[2], prev[3]);
    *(float4*)(Lr + 4) = make_float4(prev[4], prev[5], prev[6], prev[7]);
    store_minmax(prev, mm1, s * NSTRIP + sig, lane);
    int wf = __any(fgor != 0) ? 1 : 0;
    int wb = __any(bgor != 0) ? 2 : 0;
    if (lane == 0) blkflags[blockIdx.x] = wf | wb;
}

// K2: pruned bounds1 + exact pass-1 rows -> dB (+LDS) + flipped local scan -> Llast2 + mm2.
__global__ __launch_bounds__(64) void strip3ab_kernel(const int* __restrict__ tg,
                                                      const float* __restrict__ Llast,
                                                      const float* __restrict__ mm1,
                                                      float* __restrict__ dB,
                                                      float* __restrict__ Llast2,
                                                      float* __restrict__ mm2) {
    const int s = blockIdx.x >> 6, sig = blockIdx.x & 63;
    const int lane = threadIdx.x;
    const int c0 = lane * 8;
    const int* tgb = tg + (size_t)s * NPIX;
    const int R0 = sig * TST;
    float jc[8];
#pragma unroll
    for (int i = 0; i < 8; ++i) jc[i] = A_W * (float)(c0 + i);

    __shared__ float lds[TST][WDIM];   // 16 KB; single-wave block

    float prev[8];
    if (sig == 0) {
#pragma unroll
        for (int i = 0; i < 8; ++i) prev[i] = INF_W;
    } else {
        inline_bounds(Llast + (size_t)s * NSTRIP * WDIM, sig, jc, c0, prev,
                      mm1, s * NSTRIP, lane);
    }

    RowBits rA = loadrow_bits(tgb, R0 - 1, c0);
    RowBits rB = loadrow_bits(tgb, R0, c0);
    float* dst = dB + (size_t)s * NPIX + (size_t)R0 * WDIM;
#pragma unroll 2
    for (int t = 0; t < TST; ++t) {
        RowBits rC = loadrow_bits(tgb, R0 + t + 1, c0);
        int smask = (rA.efg | rB.efg | rC.efg) & (rA.ebg | rB.ebg | rC.ebg);
        float dr[8];
#pragma unroll
        for (int i = 0; i < 8; ++i) dr[i] = ((smask >> i) & 1) ? 0.f : INF_W;
        row_step(jc, prev, dr);
        float* p = dst + (size_t)t * WDIM + c0;
        *(float4*)p       = make_float4(prev[0], prev[1], prev[2], prev[3]);
        *(float4*)(p + 4) = make_float4(prev[4], prev[5], prev[6], prev[7]);
        *(float4*)&lds[t][c0]     = make_float4(prev[0], prev[1], prev[2], prev[3]);
        *(float4*)&lds[t][c0 + 4] = make_float4(prev[4], prev[5], prev[6], prev[7]);
        rA = rB; rB = rC;
    }
    __syncthreads();
    // flipped (pass-2) local scan over this strip, INF incoming
#pragma unroll
    for (int i = 0; i < 8; ++i) prev[i] = INF_W;
#pragma unroll 2
    for (int t2 = 0; t2 < TST; ++t2) {
        float4 a = *(const float4*)&lds[TST - 1 - t2][504 - c0];
        float4 q = *(const float4*)&lds[TST - 1 - t2][508 - c0];
        float dr[8];
        dr[7]=a.x; dr[6]=a.y; dr[5]=a.z; dr[4]=a.w;
        dr[3]=q.x; dr[2]=q.y; dr[1]=q.z; dr[0]=q.w;
        row_step(jc, prev, dr);
    }
    const int sig2 = NSTRIP - 1 - sig;
    float* Lr = Llast2 + ((size_t)s * NSTRIP + sig2) * WDIM + c0;
    *(float4*)Lr       = make_float4(prev[0], prev[1], prev[2], prev[3]);
    *(float4*)(Lr + 4) = make_float4(prev[4], prev[5], prev[6], prev[7]);
    store_minmax(prev, mm2, s * NSTRIP + sig2, lane);
}

// K3: pruned bounds2 + pass-2 exact rows from dB + fused loss -> sacc.
__global__ __launch_bounds__(64) void strip3bloss_kernel(const float* __restrict__ dB,
                                                         const float* __restrict__ Llast2,
                                                         const float* __restrict__ mm2,
                                                         const float* __restrict__ pred,
                                                         const int* __restrict__ tg,
                                                         float* __restrict__ sacc) {
    const int s = blockIdx.x >> 6, sig2 = blockIdx.x & 63;
    const int lane = threadIdx.x;
    const int c0 = lane * 8;
    const size_t sb = (size_t)s * NPIX;
    float jc[8];
#pragma unroll
    for (int i = 0; i < 8; ++i) jc[i] = A_W * (float)(c0 + i);

    float prev[8];
    if (sig2 == 0) {
#pragma unroll
        for (int i = 0; i < 8; ++i) prev[i] = INF_W;
    } else {
        inline_bounds(Llast2 + (size_t)s * NSTRIP * WDIM, sig2, jc, c0, prev,
                      mm2, s * NSTRIP, lane);
    }

    float mx = 0.f, facc = 0.f, s1 = 0.f, s2 = 0.f, iacc = 0.f, pacc = 0.f;
#pragma unroll 2
    for (int t = 0; t < TST; ++t) {
        int pr = HDIM - 1 - (sig2 * TST + t);
        const size_t rbase = sb + (size_t)pr * WDIM + (WDIM - 8 - c0);
        float4 a = *(const float4*)(dB + rbase);
        float4 b = *(const float4*)(dB + rbase + 4);
        float dr[8];
        dr[7]=a.x; dr[6]=a.y; dr[5]=a.z; dr[4]=a.w;
        dr[3]=b.x; dr[2]=b.y; dr[1]=b.z; dr[0]=b.w;
        float4 xa = *(const float4*)(pred + rbase);
        float4 xb = *(const float4*)(pred + rbase + 4);
        float px[8];
        px[7]=xa.x; px[6]=xa.y; px[5]=xa.z; px[4]=xa.w;
        px[3]=xb.x; px[2]=xb.y; px[1]=xb.z; px[0]=xb.w;
        int4 ta = *(const int4*)(tg + rbase);
        int4 tb = *(const int4*)(tg + rbase + 4);
        int ti[8];
        ti[7]=ta.x; ti[6]=ta.y; ti[5]=ta.z; ti[4]=ta.w;
        ti[3]=tb.x; ti[2]=tb.y; ti[1]=tb.z; ti[0]=tb.w;
        row_step(jc, prev, dr);
#pragma unroll
        for (int i = 0; i < 8; ++i) {
            float x = px[i];
            float dd = prev[i];
            float e = __expf(-fabsf(x));
            float inv = 1.f / (1.f + e);
            float pr_ = (x >= 0.f) ? inv : (1.f - inv);   // sigmoid(x)
            float L = __logf(1.f + e);                    // softplus(-|x|)
            bool t1 = ti[i] != 0;
            float fo = t1 ? 0.25f * (1.f - pr_) * (1.f - pr_) * (fmaxf(-x, 0.f) + L)
                          : 0.75f * pr_ * pr_ * (fmaxf(x, 0.f) + L);
            facc += fo;
            float base = t1 ? (1.f - pr_) : pr_;
            s1 += base;
            s2 += base * dd;
            float tf = t1 ? 1.f : 0.f;
            iacc += tf * pr_;
            pacc += pr_ + tf;
            mx = fmaxf(mx, dd);
        }
    }
#pragma unroll
    for (int off = 32; off > 0; off >>= 1) {
        facc += __shfl_xor(facc, off);
        s1   += __shfl_xor(s1, off);
        s2   += __shfl_xor(s2, off);
        iacc += __shfl_xor(iacc, off);
        pacc += __shfl_xor(pacc, off);
        mx    = fmaxf(mx, __shfl_xor(mx, off));
    }
    if (lane == 0) {
        const int idx = s * NSTRIP + sig2;
        sacc[0 * NBLK + idx] = s1;
        sacc[1 * NBLK + idx] = s2;
        sacc[2 * NBLK + idx] = iacc;
        sacc[3 * NBLK + idx] = pacc;
        sacc[4 * NBLK + idx] = mx;
        sacc[5 * NBLK + idx] = facc;
    }
}

// K4: final reduction (one 64-lane block; 64 strips/sample = one full wave per sample).
__global__ __launch_bounds__(64) void final5_kernel(const float* __restrict__ sacc,
                                                    const int* __restrict__ blkflags,
                                                    const float* __restrict__ lv,
                                                    float* __restrict__ out) {
    const int lane = threadIdx.x;
    float fsum = 0.f, bsum = 0.f, dsum = 0.f, isum = 0.f;
    for (int ss = 0; ss < NSAMP; ++ss) {
        int idx = ss * NSTRIP + lane;
        float t1 = sacc[0 * NBLK + idx];
        float t2 = sacc[1 * NBLK + idx];
        float ia = sacc[2 * NBLK + idx];
        float pa = sacc[3 * NBLK + idx];
        float mxs = sacc[4 * NBLK + idx];
        float fa = sacc[5 * NBLK + idx];
        int   vv = blkflags[idx];
#pragma unroll
        for (int off = 32; off > 0; off >>= 1) {
            t1 += __shfl_xor(t1, off);
            t2 += __shfl_xor(t2, off);
            ia += __shfl_xor(ia, off);
            pa += __shfl_xor(pa, off);
            fa += __shfl_xor(fa, off);
            mxs = fmaxf(mxs, __shfl_xor(mxs, off));
            vv |= __shfl_xor(vv, off);
        }
        bool hasb = (vv & 3) == 3;     // boundary nonempty (has_fg && has_bg)
        fsum += fa;
        // hasb: dist = d/mx (mx>0). !hasb: dist ≡ 1 (all-fg and all-bg alike) -> S1.
        float distsum = hasb ? ((mxs > 0.f) ? t2 / fmaxf(mxs, 1e-12f) : 0.f) : t1;
        bsum += t1 + distsum;
        dsum += (2.f * ia + 1e-6f) / (pa + 1e-6f);
        isum += (ia + 1e-6f) / (pa - ia + 1e-6f);
    }
    if (lane == 0) {
        float focal = fsum / NTOT_F;
        float bnd   = bsum / NTOT_F;
        float dice = 1.f - dsum / 16.f;
        float iou  = 1.f - isum / 16.f;
        float l0 = lv[0], l1 = lv[1], l2 = lv[2], l3 = lv[3];
        float total = expf(-l0) * focal + l0 + expf(-l1) * dice + l1
                    + expf(-l2) * bnd  + l2 + expf(-l3) * iou  + l3;
        out[0] = total; out[1] = focal; out[2] = dice; out[3] = bnd; out[4] = iou;
    }
}

extern "C" void kernel_launch(void* const* d_in, const int* in_sizes, int n_in,
                              void* d_out, int out_size, void* d_ws, size_t ws_size,
                              hipStream_t stream) {
    const float* pred = (const float*)d_in[0];
    const int*   tg   = (const int*)d_in[1];
    const float* lv   = (const float*)d_in[2];
    float* out = (float*)d_out;
    char* ws = (char*)d_ws;
    int*   blkflags = (int*)(ws + 1024);
    float* sacc     = (float*)(ws + OFF_SACC);
    float* mm1      = (float*)(ws + OFF_MM1);
    float* mm2      = (float*)(ws + OFF_MM2);
    float* Llast    = (float*)(ws + OFF_LLAST);
    float* Llast2   = (float*)(ws + OFF_LLAST2);
    float* dB       = (float*)(ws + OFF_DB);

    strip1a_kernel<<<NBLK, 64, 0, stream>>>(tg, Llast, mm1, blkflags);
    strip3ab_kernel<<<NBLK, 64, 0, stream>>>(tg, Llast, mm1, dB, Llast2, mm2);
    strip3bloss_kernel<<<NBLK, 64, 0, stream>>>(dB, Llast2, mm2, pred, tg, sacc);
    final5_kernel<<<1, 64, 0, stream>>>(sacc, blkflags, lv, out);
}

// Round 16
// 114.085 us; speedup vs baseline: 1.2593x; 1.0294x over previous
//
#include <hip/hip_runtime.h>
#include <math.h>

#define A_W 0.955f
#define B_W 1.3693f
#define INF_W 1e6f
#define HDIM 512
#define WDIM 512
#define NPIX (HDIM*WDIM)
#define NSAMP 16
#define NTOT_F 4194304.0f
#define TST 4        // strip height
#define NSTRIP 128   // strips per sample
#define NBLK (NSAMP*NSTRIP)        // 2048
#define STRIP_COST (4.0f * A_W)    // min cost to propagate a boundary through one strip

// ws layout (bytes):
//  [1024,9216):     int blkflags[2048]  (per strip: bit0=has_fg, bit1=has_bg)
//  [16384,65536):   float sacc[6][2048]
//  [65536,81920):   float mm1[2][2048]  (min,max of Llast rows)
//  [81920,98304):   float mm2[2][2048]  (min,max of Llast2 rows)
//  [1MB,5MB):       float Llast[16][128][512]
//  [5MB,9MB):       float Llast2[16][128][512]
//  [9MB,25MB):      float dB[16][512][512]
#define OFF_FLAGS  1024
#define OFF_SACC   16384
#define OFF_MM1    65536
#define OFF_MM2    81920
#define OFF_LLAST  (1u<<20)
#define OFF_LLAST2 (5u<<20)
#define OFF_DB     (9u<<20)

// DPP move with INF fill (floats).
//   WAVE_SHR1 (0x138): lane i <- lane i-1 (== __shfl_up 1)
//   WAVE_SHL1 (0x130): lane i <- lane i+1 (== __shfl_down 1)
template<int CTRL, int RMASK>
__device__ __forceinline__ float dpp_mov_inf(float x) {
    return __int_as_float(__builtin_amdgcn_update_dpp(
        __float_as_int(INF_W), __float_as_int(x), CTRL, RMASK, 0xF, false));
}
template<int CTRL>
__device__ __forceinline__ int dpp_mov0_i(int x) {
    return __builtin_amdgcn_update_dpp(0, x, CTRL, 0xF, 0xF, true);
}

__device__ __forceinline__ float wave_prefix_min_incl(float t) {
    t = fminf(t, dpp_mov_inf<0x111,0xF>(t));
    t = fminf(t, dpp_mov_inf<0x112,0xF>(t));
    t = fminf(t, dpp_mov_inf<0x114,0xF>(t));
    t = fminf(t, dpp_mov_inf<0x118,0xF>(t));
    t = fminf(t, dpp_mov_inf<0x142,0xA>(t));
    t = fminf(t, dpp_mov_inf<0x143,0xC>(t));
    return t;
}

__device__ __forceinline__ void cummin_row(const float* jc, float* v) {
    float g[8];
#pragma unroll
    for (int i = 0; i < 8; ++i) g[i] = v[i] - jc[i];
    float c1[8];
    c1[0] = g[0];
#pragma unroll
    for (int i = 1; i < 8; ++i) c1[i] = fminf(g[i], g[i-1]);
    float c2[8];
    c2[0] = c1[0]; c2[1] = c1[1];
#pragma unroll
    for (int i = 2; i < 8; ++i) c2[i] = fminf(c1[i], c1[i-2]);
    float cj[8];
    cj[0] = c2[0]; cj[1] = c2[1]; cj[2] = c2[2]; cj[3] = c2[3];
#pragma unroll
    for (int i = 4; i < 8; ++i) cj[i] = fminf(c2[i], c2[i-4]);
    float t  = wave_prefix_min_incl(cj[7]);
    float ex = dpp_mov_inf<0x138,0xF>(t);
#pragma unroll
    for (int i = 0; i < 8; ++i) v[i] = jc[i] + fminf(cj[i], ex);
}

__device__ __forceinline__ void row_step(const float* jc, float* prev, const float* drow) {
    float lIn = dpp_mov_inf<0x138,0xF>(prev[7]);
    float rIn = dpp_mov_inf<0x130,0xF>(prev[0]);
    float m[8];
#pragma unroll
    for (int i = 0; i < 8; ++i) {
        float up = prev[i] + A_W;
        float ul = ((i == 0) ? lIn : prev[i-1]) + B_W;
        float ur = ((i == 7) ? rIn : prev[i+1]) + B_W;
        m[i] = fminf(fminf(drow[i], up), fminf(ul, ur));
    }
    cummin_row(jc, m);
#pragma unroll
    for (int i = 0; i < 8; ++i) prev[i] = m[i];
}

// 4 fused T3 steps (exact, INF outside grid). T3^4 == one call (TST==4).
__device__ __forceinline__ void t3x4(float* b) {
    float e[16];
#pragma unroll
    for (int k = 0; k < 4; ++k) e[k]    = dpp_mov_inf<0x138,0xF>(b[4+k]);
#pragma unroll
    for (int k = 0; k < 8; ++k) e[4+k]  = b[k];
#pragma unroll
    for (int k = 0; k < 4; ++k) e[12+k] = dpp_mov_inf<0x130,0xF>(b[k]);
    const float w0 = 4.f*A_W, w1 = 3.f*A_W + B_W, w2 = 2.f*A_W + 2.f*B_W;
    const float w3 = A_W + 3.f*B_W, w4 = 4.f*B_W;
#pragma unroll
    for (int i = 0; i < 8; ++i) {
        float m = e[i+4] + w0;
        m = fminf(m, fminf(e[i+3], e[i+5]) + w1);
        m = fminf(m, fminf(e[i+2], e[i+6]) + w2);
        m = fminf(m, fminf(e[i+1], e[i+7]) + w3);
        m = fminf(m, fminf(e[i+0], e[i+8]) + w4);
        b[i] = m;
    }
}

struct RowBits { int efg; int ebg; int rawbg; };

__device__ __forceinline__ RowBits make_rowbits(uint4 a, uint4 b) {
    int fg = ((a.x!=0u)?1:0) | ((a.y!=0u)?2:0) | ((a.z!=0u)?4:0) | ((a.w!=0u)?8:0)
           | ((b.x!=0u)?16:0) | ((b.y!=0u)?32:0) | ((b.z!=0u)?64:0) | ((b.w!=0u)?128:0);
    int bg = (~fg) & 0xFF;
    int lf = dpp_mov0_i<0x138>(fg), rf = dpp_mov0_i<0x130>(fg);
    int lb = dpp_mov0_i<0x138>(bg), rb = dpp_mov0_i<0x130>(bg);
    RowBits r;
    r.efg = (fg | (fg<<1) | (fg>>1) | ((lf>>7)&1) | ((rf&1)<<7)) & 0xFF;
    r.ebg = (bg | (bg<<1) | (bg>>1) | ((lb>>7)&1) | ((rb&1)<<7)) & 0xFF;
    r.rawbg = bg;
    return r;
}

__device__ __forceinline__ RowBits loadrow_bits(const int* tgb, int rr, int c0) {
    if (rr < 0 || rr >= HDIM) { RowBits z; z.efg = 0; z.ebg = 0; z.rawbg = 0; return z; }
    const uint4* p = (const uint4*)(tgb + (size_t)rr * WDIM + c0);
    return make_rowbits(p[0], p[1]);
}

// store min/max of an L row (prev[8] across wave) into mm arrays
__device__ __forceinline__ void store_minmax(const float* prev, float* __restrict__ mm,
                                             int idx, int lane) {
    float mn = prev[0], mx = prev[0];
#pragma unroll
    for (int i = 1; i < 8; ++i) { mn = fminf(mn, prev[i]); mx = fmaxf(mx, prev[i]); }
#pragma unroll
    for (int off = 32; off > 0; off >>= 1) {
        mn = fminf(mn, __shfl_xor(mn, off));
        mx = fmaxf(mx, __shfl_xor(mx, off));
    }
    if (lane == 0) { mm[idx] = mn; mm[NBLK + idx] = mx; }
}

// Inline exact boundary with dominance pruning over up to 127 strips (two 64-wide
// ballot segments). Strip k skippable when minL[k] + STRIP_COST*(n-1-k) > maxL[n-1]
// (each propagated row adds >= A; b*[j] <= L[n-1][j] <= maxL[n-1]). Ties kept -> exact.
__device__ __forceinline__ void inline_bounds(const float* __restrict__ Lb, int n,
                                              const float* jc, int c0, float* prev,
                                              const float* __restrict__ mm, int base,
                                              int lane) {
    float ub = mm[NBLK + base + (n - 1)];                // maxL[n-1]
    int k0 = n - 1;
    {
        int k = lane;
        bool c = (k < n) && (mm[base + k] + STRIP_COST * (float)(n - 1 - k) <= ub);
        unsigned long long m0 = __ballot((int)c);
        if (m0 != 0ull) {
            k0 = __ffsll((long long)m0) - 1;
        } else if (n > 64) {
            k = 64 + lane;
            bool c1 = (k < n) && (mm[base + k] + STRIP_COST * (float)(n - 1 - k) <= ub);
            unsigned long long m1 = __ballot((int)c1);
            if (m1 != 0ull) k0 = 64 + __ffsll((long long)m1) - 1;
        }
    }

    float b[8];
    const float* Lr = Lb + (size_t)k0 * WDIM + c0;
    float4 l0 = *(const float4*)Lr;
    float4 l1 = *(const float4*)(Lr + 4);
    b[0]=l0.x; b[1]=l0.y; b[2]=l0.z; b[3]=l0.w;
    b[4]=l1.x; b[5]=l1.y; b[6]=l1.z; b[7]=l1.w;
    for (int sg = k0 + 1; sg < n; ++sg) {
        const float* Ls = Lb + (size_t)sg * WDIM + c0;
        float4 m0 = *(const float4*)Ls;
        float4 m1 = *(const float4*)(Ls + 4);
        t3x4(b);                                 // T3^4 exact (TST==4)
        cummin_row(jc, b);
        b[0]=fminf(b[0],m0.x); b[1]=fminf(b[1],m0.y); b[2]=fminf(b[2],m0.z); b[3]=fminf(b[3],m0.w);
        b[4]=fminf(b[4],m1.x); b[5]=fminf(b[5],m1.y); b[6]=fminf(b[6],m1.z); b[7]=fminf(b[7],m1.w);
    }
#pragma unroll
    for (int i = 0; i < 8; ++i) prev[i] = b[i];
}

// K1: pass-1 local strip scan (boundary seeds; INF incoming) -> Llast + mm1 + flags.
__global__ __launch_bounds__(64) void strip1a_kernel(const int* __restrict__ tg,
                                                     float* __restrict__ Llast,
                                                     float* __restrict__ mm1,
                                                     int* __restrict__ blkflags) {
    const int s = blockIdx.x >> 7, sig = blockIdx.x & 127;
    const int lane = threadIdx.x;
    const int c0 = lane * 8;
    const int* tgb = tg + (size_t)s * NPIX;
    const int R0 = sig * TST;
    float jc[8];
#pragma unroll
    for (int i = 0; i < 8; ++i) jc[i] = A_W * (float)(c0 + i);
    RowBits rA = loadrow_bits(tgb, R0 - 1, c0);
    RowBits rB = loadrow_bits(tgb, R0, c0);
    float prev[8];
#pragma unroll
    for (int i = 0; i < 8; ++i) prev[i] = INF_W;
    int fgor = 0, bgor = 0;
#pragma unroll
    for (int t = 0; t < TST; ++t) {
        RowBits rC = loadrow_bits(tgb, R0 + t + 1, c0);
        fgor |= (~rB.rawbg) & 0xFF;
        bgor |= rB.rawbg;
        int smask = (rA.efg | rB.efg | rC.efg) & (rA.ebg | rB.ebg | rC.ebg);
        float dr[8];
#pragma unroll
        for (int i = 0; i < 8; ++i) dr[i] = ((smask >> i) & 1) ? 0.f : INF_W;
        row_step(jc, prev, dr);
        rA = rB; rB = rC;
    }
    float* Lr = Llast + ((size_t)s * NSTRIP + sig) * WDIM + c0;
    *(float4*)Lr       = make_float4(prev[0], prev[1], prev[2], prev[3]);
    *(float4*)(Lr + 4) = make_float4(prev[4], prev[5], prev[6], prev[7]);
    store_minmax(prev, mm1, s * NSTRIP + sig, lane);
    int wf = __any(fgor != 0) ? 1 : 0;
    int wb = __any(bgor != 0) ? 2 : 0;
    if (lane == 0) blkflags[blockIdx.x] = wf | wb;
}

// K2: pruned bounds1 + exact pass-1 rows -> dB (+LDS) + flipped local scan -> Llast2 + mm2.
__global__ __launch_bounds__(64) void strip3ab_kernel(const int* __restrict__ tg,
                                                      const float* __restrict__ Llast,
                                                      const float* __restrict__ mm1,
                                                      float* __restrict__ dB,
                                                      float* __restrict__ Llast2,
                                                      float* __restrict__ mm2) {
    const int s = blockIdx.x >> 7, sig = blockIdx.x & 127;
    const int lane = threadIdx.x;
    const int c0 = lane * 8;
    const int* tgb = tg + (size_t)s * NPIX;
    const int R0 = sig * TST;
    float jc[8];
#pragma unroll
    for (int i = 0; i < 8; ++i) jc[i] = A_W * (float)(c0 + i);

    __shared__ float lds[TST][WDIM];   // 8 KB; single-wave block

    float prev[8];
    if (sig == 0) {
#pragma unroll
        for (int i = 0; i < 8; ++i) prev[i] = INF_W;
    } else {
        inline_bounds(Llast + (size_t)s * NSTRIP * WDIM, sig, jc, c0, prev,
                      mm1, s * NSTRIP, lane);
    }

    RowBits rA = loadrow_bits(tgb, R0 - 1, c0);
    RowBits rB = loadrow_bits(tgb, R0, c0);
    float* dst = dB + (size_t)s * NPIX + (size_t)R0 * WDIM;
#pragma unroll
    for (int t = 0; t < TST; ++t) {
        RowBits rC = loadrow_bits(tgb, R0 + t + 1, c0);
        int smask = (rA.efg | rB.efg | rC.efg) & (rA.ebg | rB.ebg | rC.ebg);
        float dr[8];
#pragma unroll
        for (int i = 0; i < 8; ++i) dr[i] = ((smask >> i) & 1) ? 0.f : INF_W;
        row_step(jc, prev, dr);
        float* p = dst + (size_t)t * WDIM + c0;
        *(float4*)p       = make_float4(prev[0], prev[1], prev[2], prev[3]);
        *(float4*)(p + 4) = make_float4(prev[4], prev[5], prev[6], prev[7]);
        *(float4*)&lds[t][c0]     = make_float4(prev[0], prev[1], prev[2], prev[3]);
        *(float4*)&lds[t][c0 + 4] = make_float4(prev[4], prev[5], prev[6], prev[7]);
        rA = rB; rB = rC;
    }
    __syncthreads();
    // flipped (pass-2) local scan over this strip, INF incoming
#pragma unroll
    for (int i = 0; i < 8; ++i) prev[i] = INF_W;
#pragma unroll
    for (int t2 = 0; t2 < TST; ++t2) {
        float4 a = *(const float4*)&lds[TST - 1 - t2][504 - c0];
        float4 q = *(const float4*)&lds[TST - 1 - t2][508 - c0];
        float dr[8];
        dr[7]=a.x; dr[6]=a.y; dr[5]=a.z; dr[4]=a.w;
        dr[3]=q.x; dr[2]=q.y; dr[1]=q.z; dr[0]=q.w;
        row_step(jc, prev, dr);
    }
    const int sig2 = NSTRIP - 1 - sig;
    float* Lr = Llast2 + ((size_t)s * NSTRIP + sig2) * WDIM + c0;
    *(float4*)Lr       = make_float4(prev[0], prev[1], prev[2], prev[3]);
    *(float4*)(Lr + 4) = make_float4(prev[4], prev[5], prev[6], prev[7]);
    store_minmax(prev, mm2, s * NSTRIP + sig2, lane);
}

// K3: pruned bounds2 + pass-2 exact rows from dB + fused loss -> sacc.
__global__ __launch_bounds__(64) void strip3bloss_kernel(const float* __restrict__ dB,
                                                         const float* __restrict__ Llast2,
                                                         const float* __restrict__ mm2,
                                                         const float* __restrict__ pred,
                                                         const int* __restrict__ tg,
                                                         float* __restrict__ sacc) {
    const int s = blockIdx.x >> 7, sig2 = blockIdx.x & 127;
    const int lane = threadIdx.x;
    const int c0 = lane * 8;
    const size_t sb = (size_t)s * NPIX;
    float jc[8];
#pragma unroll
    for (int i = 0; i < 8; ++i) jc[i] = A_W * (float)(c0 + i);

    float prev[8];
    if (sig2 == 0) {
#pragma unroll
        for (int i = 0; i < 8; ++i) prev[i] = INF_W;
    } else {
        inline_bounds(Llast2 + (size_t)s * NSTRIP * WDIM, sig2, jc, c0, prev,
                      mm2, s * NSTRIP, lane);
    }

    float mx = 0.f, facc = 0.f, s1 = 0.f, s2 = 0.f, iacc = 0.f, pacc = 0.f;
#pragma unroll 2
    for (int t = 0; t < TST; ++t) {
        int pr = HDIM - 1 - (sig2 * TST + t);
        const size_t rbase = sb + (size_t)pr * WDIM + (WDIM - 8 - c0);
        float4 a = *(const float4*)(dB + rbase);
        float4 b = *(const float4*)(dB + rbase + 4);
        float dr[8];
        dr[7]=a.x; dr[6]=a.y; dr[5]=a.z; dr[4]=a.w;
        dr[3]=b.x; dr[2]=b.y; dr[1]=b.z; dr[0]=b.w;
        float4 xa = *(const float4*)(pred + rbase);
        float4 xb = *(const float4*)(pred + rbase + 4);
        float px[8];
        px[7]=xa.x; px[6]=xa.y; px[5]=xa.z; px[4]=xa.w;
        px[3]=xb.x; px[2]=xb.y; px[1]=xb.z; px[0]=xb.w;
        int4 ta = *(const int4*)(tg + rbase);
        int4 tb = *(const int4*)(tg + rbase + 4);
        int ti[8];
        ti[7]=ta.x; ti[6]=ta.y; ti[5]=ta.z; ti[4]=ta.w;
        ti[3]=tb.x; ti[2]=tb.y; ti[1]=tb.z; ti[0]=tb.w;
        row_step(jc, prev, dr);
#pragma unroll
        for (int i = 0; i < 8; ++i) {
            float x = px[i];
            float dd = prev[i];
            float e = __expf(-fabsf(x));
            float inv = 1.f / (1.f + e);
            float pr_ = (x >= 0.f) ? inv : (1.f - inv);   // sigmoid(x)
            float L = __logf(1.f + e);                    // softplus(-|x|)
            bool t1 = ti[i] != 0;
            float fo = t1 ? 0.25f * (1.f - pr_) * (1.f - pr_) * (fmaxf(-x, 0.f) + L)
                          : 0.75f * pr_ * pr_ * (fmaxf(x, 0.f) + L);
            facc += fo;
            float base = t1 ? (1.f - pr_) : pr_;
            s1 += base;
            s2 += base * dd;
            float tf = t1 ? 1.f : 0.f;
            iacc += tf * pr_;
            pacc += pr_ + tf;
            mx = fmaxf(mx, dd);
        }
    }
#pragma unroll
    for (int off = 32; off > 0; off >>= 1) {
        facc += __shfl_xor(facc, off);
        s1   += __shfl_xor(s1, off);
        s2   += __shfl_xor(s2, off);
        iacc += __shfl_xor(iacc, off);
        pacc += __shfl_xor(pacc, off);
        mx    = fmaxf(mx, __shfl_xor(mx, off));
    }
    if (lane == 0) {
        const int idx = s * NSTRIP + sig2;
        sacc[0 * NBLK + idx] = s1;
        sacc[1 * NBLK + idx] = s2;
        sacc[2 * NBLK + idx] = iacc;
        sacc[3 * NBLK + idx] = pacc;
        sacc[4 * NBLK + idx] = mx;
        sacc[5 * NBLK + idx] = facc;
    }
}

// K4: final reduction (one 64-lane block; 128 strips/sample = two entries per lane).
__global__ __launch_bounds__(64) void final5_kernel(const float* __restrict__ sacc,
                                                    const int* __restrict__ blkflags,
                                                    const float* __restrict__ lv,
                                                    float* __restrict__ out) {
    const int lane = threadIdx.x;
    float fsum = 0.f, bsum = 0.f, dsum = 0.f, isum = 0.f;
    for (int ss = 0; ss < NSAMP; ++ss) {
        int i0 = ss * NSTRIP + lane, i1 = i0 + 64;
        float t1 = sacc[0 * NBLK + i0] + sacc[0 * NBLK + i1];
        float t2 = sacc[1 * NBLK + i0] + sacc[1 * NBLK + i1];
        float ia = sacc[2 * NBLK + i0] + sacc[2 * NBLK + i1];
        float pa = sacc[3 * NBLK + i0] + sacc[3 * NBLK + i1];
        float mxs = fmaxf(sacc[4 * NBLK + i0], sacc[4 * NBLK + i1]);
        float fa = sacc[5 * NBLK + i0] + sacc[5 * NBLK + i1];
        int   vv = blkflags[i0] | blkflags[i1];
#pragma unroll
        for (int off = 32; off > 0; off >>= 1) {
            t1 += __shfl_xor(t1, off);
            t2 += __shfl_xor(t2, off);
            ia += __shfl_xor(ia, off);
            pa += __shfl_xor(pa, off);
            fa += __shfl_xor(fa, off);
            mxs = fmaxf(mxs, __shfl_xor(mxs, off));
            vv |= __shfl_xor(vv, off);
        }
        bool hasb = (vv & 3) == 3;     // boundary nonempty (has_fg && has_bg)
        fsum += fa;
        // hasb: dist = d/mx (mx>0). !hasb: dist ≡ 1 (all-fg and all-bg alike) -> S1.
        float distsum = hasb ? ((mxs > 0.f) ? t2 / fmaxf(mxs, 1e-12f) : 0.f) : t1;
        bsum += t1 + distsum;
        dsum += (2.f * ia + 1e-6f) / (pa + 1e-6f);
        isum += (ia + 1e-6f) / (pa - ia + 1e-6f);
    }
    if (lane == 0) {
        float focal = fsum / NTOT_F;
        float bnd   = bsum / NTOT_F;
        float dice = 1.f - dsum / 16.f;
        float iou  = 1.f - isum / 16.f;
        float l0 = lv[0], l1 = lv[1], l2 = lv[2], l3 = lv[3];
        float total = expf(-l0) * focal + l0 + expf(-l1) * dice + l1
                    + expf(-l2) * bnd  + l2 + expf(-l3) * iou  + l3;
        out[0] = total; out[1] = focal; out[2] = dice; out[3] = bnd; out[4] = iou;
    }
}

extern "C" void kernel_launch(void* const* d_in, const int* in_sizes, int n_in,
                              void* d_out, int out_size, void* d_ws, size_t ws_size,
                              hipStream_t stream) {
    const float* pred = (const float*)d_in[0];
    const int*   tg   = (const int*)d_in[1];
    const float* lv   = (const float*)d_in[2];
    float* out = (float*)d_out;
    char* ws = (char*)d_ws;
    int*   blkflags = (int*)(ws + OFF_FLAGS);
    float* sacc     = (float*)(ws + OFF_SACC);
    float* mm1      = (float*)(ws + OFF_MM1);
    float* mm2      = (float*)(ws + OFF_MM2);
    float* Llast    = (float*)(ws + OFF_LLAST);
    float* Llast2   = (float*)(ws + OFF_LLAST2);
    float* dB       = (float*)(ws + OFF_DB);

    strip1a_kernel<<<NBLK, 64, 0, stream>>>(tg, Llast, mm1, blkflags);
    strip3ab_kernel<<<NBLK, 64, 0, stream>>>(tg, Llast, mm1, dB, Llast2, mm2);
    strip3bloss_kernel<<<NBLK, 64, 0, stream>>>(dB, Llast2, mm2, pred, tg, sacc);
    final5_kernel<<<1, 64, 0, stream>>>(sacc, blkflags, lv, out);
}